// Round 3
// baseline (292.874 us; speedup 1.0000x reference)
//
#include <hip/hip_runtime.h>

// SAGAN self-attention, B=4, C=512, Cp=64, N=64*64=4096. fp32 in/out
// (runtime-detected). All tensors between stages live in MFMA fragment-
// order layouts (lane-linear loads). proj fused (x read once, f/g/h in one
// pass; log2e folded into Wf so softmax uses raw v_exp_f32). 1/l folded
// into V by scalehx (in-place). pv: 4 waves = 2 igrp x 2 jgrp, j-sub 32
// per wave, full c, acc 32 AGPR, <=128 regs -> 4 waves/SIMD. pv writes
// outproj's A-frag layout (4 fp32 partial buffers, summed in registers).
//
// fxF/gxF layout (32x32x16 A/B frag, 32-row n-tiles, K=Cp):
//   off(b,tile,kc,l,e) = (((b*128+tile)*4+kc)*64+l)*8+e
//   content: (n = tile*32 + (l&31), c = kc*16 + (l>>5)*8 + e)
// hxF layout (PV B-frag, 32-i tiles):
//   off(b,tile,ich,part,l,e) = ((((b*128+tile)*2+ich)*2+part)*64+l)*8+e
//   content: (c = part*32 + (l&31), i = tile*32 + ich*16 + (l>>5)*8 + e)
// opF layout (16x16x32 A-frag for outproj), per isb buffer:
//   off(b,nt,ks,l,e) = (((b*256+nt)*2+ks)*64+l)*8+e
//   content: (n = nt*16 + (l&15), cp = ks*32 + (l>>4)*8 + e)

#define NB 4
#define CC 512
#define CP 64
#define NN 4096
#define L2E 1.4426950408889634f

typedef __attribute__((ext_vector_type(8))) short short8;
typedef __attribute__((ext_vector_type(4))) float floatx4;
typedef __attribute__((ext_vector_type(16))) float floatx16;

#define MFMA32(A, B, C) __builtin_amdgcn_mfma_f32_32x32x16_bf16((A), (B), (C), 0, 0, 0)

__device__ __forceinline__ float bf2f_u(unsigned short h) {
    return __uint_as_float((unsigned)h << 16);
}
__device__ __forceinline__ float bf16lo(unsigned v) { return __uint_as_float(v << 16); }
__device__ __forceinline__ float bf16hi(unsigned v) { return __uint_as_float(v & 0xffff0000u); }
__device__ __forceinline__ unsigned short f2bf(float f) {
    unsigned u = __float_as_uint(f);
    u += 0x7fffu + ((u >> 16) & 1u);   // RNE
    return (unsigned short)(u >> 16);
}
__device__ __forceinline__ unsigned pack2bf(float a, float b) {
    return (unsigned)f2bf(a) | ((unsigned)f2bf(b) << 16);
}
__device__ __forceinline__ float ldS(const void* p, long i, int f32) {
    return f32 ? ((const float*)p)[i] : bf2f_u(((const unsigned short*)p)[i]);
}
__device__ __forceinline__ float2 ld2(const void* p, long i, int f32) {
    if (f32) return *reinterpret_cast<const float2*>((const float*)p + i);
    unsigned v = *reinterpret_cast<const unsigned*>((const unsigned short*)p + i);
    return make_float2(bf16lo(v), bf16hi(v));
}
__device__ __forceinline__ float4 ld4(const void* p, long i, int f32) {
    if (f32) return *reinterpret_cast<const float4*>((const float*)p + i);
    uint2 v = *reinterpret_cast<const uint2*>((const unsigned short*)p + i);
    return make_float4(bf16lo(v.x), bf16hi(v.x), bf16lo(v.y), bf16hi(v.y));
}
__device__ __forceinline__ short8 frag8(const void* p, long i, int f32) {
    uint4 au;
    if (f32) {
        float4 v0 = *reinterpret_cast<const float4*>((const float*)p + i);
        float4 v1 = *reinterpret_cast<const float4*>((const float*)p + i + 4);
        au.x = pack2bf(v0.x, v0.y); au.y = pack2bf(v0.z, v0.w);
        au.z = pack2bf(v1.x, v1.y); au.w = pack2bf(v1.z, v1.w);
    } else {
        au = *reinterpret_cast<const uint4*>((const unsigned short*)p + i);
    }
    return *reinterpret_cast<short8*>(&au);
}
__device__ __forceinline__ short8 as_s8(uint4 v) { return *reinterpret_cast<short8*>(&v); }
__device__ __forceinline__ floatx16 zero16() {
    floatx16 z;
    #pragma unroll
    for (int i = 0; i < 16; ++i) z[i] = 0.f;
    return z;
}
__device__ __forceinline__ unsigned cvtpk_bf16(float a, float b) {
    unsigned r;
    asm("v_cvt_pk_bf16_f32 %0, %1, %2" : "=v"(r) : "v"(a), "v"(b));
    return r;
}
__device__ __forceinline__ void pl32swap(unsigned &a, unsigned &b) {
    asm("v_permlane32_swap_b32 %0, %1" : "+v"(a), "+v"(b));
}
__device__ __forceinline__ float rcpf(float x) {
    float r;
    asm("v_rcp_f32 %0, %1" : "=v"(r) : "v"(x));
    return r;
}
__device__ __forceinline__ float exp2a(float x) {   // 2^x
    float r;
    asm("v_exp_f32 %0, %1" : "=v"(r) : "v"(x));
    return r;
}

// ---------------------------------------------------------------------------
// dtype detector: 1 if fp32, 0 if bf16.
// ---------------------------------------------------------------------------
__global__ __launch_bounds__(256) void detect_kernel(
    const unsigned* __restrict__ x, int* __restrict__ flag)
{
    __shared__ int red[256];
    const int t = threadIdx.x;
    int bad = 0;
    for (int i = t; i < 4096; i += 256) {
        unsigned w = x[i];
        float f0 = __uint_as_float(w << 16);
        float f1 = __uint_as_float(w & 0xffff0000u);
        float a0 = fabsf(f0), a1 = fabsf(f1);
        if (!(a0 <= 1e3f) || (f0 != 0.f && a0 < 1e-20f)) bad++;
        if (!(a1 <= 1e3f) || (f1 != 0.f && a1 < 1e-20f)) bad++;
    }
    red[t] = bad;
    __syncthreads();
    for (int s = 128; s > 0; s >>= 1) { if (t < s) red[t] += red[t + s]; __syncthreads(); }
    if (t == 0) *flag = (red[0] > 64) ? 1 : 0;
}

// ---------------------------------------------------------------------------
// sigma: a = W^T u; sigma = ||a||^2 / (||a||+eps); writes 1/sigma.
// ---------------------------------------------------------------------------
__global__ __launch_bounds__(512) void sigma_kernel(
    const void* __restrict__ Wf, const void* __restrict__ Wg,
    const void* __restrict__ Wh, const void* __restrict__ Wv,
    const void* __restrict__ uf, const void* __restrict__ ug,
    const void* __restrict__ uh, const void* __restrict__ uv,
    const int* __restrict__ dflag, float* __restrict__ sig)
{
    const int f32 = *dflag;
    const int w = blockIdx.x;
    const void* W;
    const void* u;
    if (w == 0)      { W = Wf; u = uf; }
    else if (w == 1) { W = Wg; u = ug; }
    else if (w == 2) { W = Wh; u = uh; }
    else             { W = Wv; u = uv; }

    __shared__ float us[512];
    __shared__ float red[512];
    const int t = threadIdx.x;
    float S;

    if (w < 3) {
        if (t < 64) us[t] = ldS(u, t, f32);
        __syncthreads();
        float a = 0.f;
        #pragma unroll
        for (int i = 0; i < 64; ++i)
            a = fmaf(ldS(W, (long)i * 512 + t, f32), us[i], a);
        red[t] = a * a;
        __syncthreads();
        #pragma unroll
        for (int s = 256; s > 0; s >>= 1) {
            if (t < s) red[t] += red[t + s];
            __syncthreads();
        }
        S = red[0];
    } else {
        us[t] = ldS(u, t, f32);
        __syncthreads();
        const int g = t >> 6, c = t & 63;
        float a = 0.f;
        #pragma unroll
        for (int k = 0; k < 64; ++k) {
            int i = g + k * 8;
            a = fmaf(ldS(W, (long)i * 64 + c, f32), us[i], a);
        }
        red[t] = a;
        __syncthreads();
        #pragma unroll
        for (int s = 256; s >= 64; s >>= 1) {
            if (t < s) red[t] += red[t + s];
            __syncthreads();
        }
        float ac = (t < 64) ? red[t] : 0.f;
        __syncthreads();
        red[t] = ac * ac;
        __syncthreads();
        #pragma unroll
        for (int s = 256; s > 0; s >>= 1) {
            if (t < s) red[t] += red[t + s];
            __syncthreads();
        }
        S = red[0];
    }
    if (t == 0) sig[w] = (sqrtf(S) + 1e-12f) / S;
}

// ---------------------------------------------------------------------------
// proj (fused, MFMA): computes f,g,h projections in ONE pass over x.
// out^T[n][c] = sum_k x^T[n][k] * (W/sigma)^T[k][c] for each of 3 weights.
// Wf staged with extra log2e so downstream softmax uses raw v_exp_f32.
// ---------------------------------------------------------------------------
__global__ __launch_bounds__(256) void proj_kernel(
    const void* __restrict__ x,
    const void* __restrict__ Wf,
    const void* __restrict__ Wg,
    const void* __restrict__ Wh,
    const int* __restrict__ dflag,
    const float* __restrict__ sig,
    unsigned short* __restrict__ fxF, unsigned short* __restrict__ gxF,
    unsigned short* __restrict__ hxF)
{
    const int f32 = *dflag;
    const int n0 = blockIdx.x * 64;
    const int b  = blockIdx.y;

    __shared__ unsigned short Wl[3][64][72];   // [wi][c][kk]

    const int t = threadIdx.x;
    const int wv = t >> 6, l = t & 63, l15 = l & 15, quad = l >> 4;
    const int n = n0 + 16 * wv + l15;

    float sc[3];
    sc[0] = sig[0] * L2E;
    sc[1] = sig[1];
    sc[2] = sig[2];
    const void* Ws[3] = {Wf, Wg, Wh};

    floatx4 acc[3][4];
    #pragma unroll
    for (int wi = 0; wi < 3; ++wi)
        #pragma unroll
        for (int ct = 0; ct < 4; ++ct) acc[wi][ct] = (floatx4){0.f, 0.f, 0.f, 0.f};

    for (int kc = 0; kc < CC; kc += 64) {
        #pragma unroll
        for (int idx = t; idx < 6144; idx += 256) {
            int wi  = idx >> 11;
            int rem = idx & 2047;
            int c   = rem >> 5;
            int kk  = (rem & 31) * 2;
            float2 v = ld2(Ws[wi], (long)c * CC + kc + kk, f32);
            *reinterpret_cast<unsigned*>(&Wl[wi][c][kk]) =
                pack2bf(v.x * sc[wi], v.y * sc[wi]);
        }
        __syncthreads();

        #pragma unroll
        for (int ks = 0; ks < 2; ++ks) {
            const int kbase = kc + ks * 32 + quad * 8;
            float xv[8];
            #pragma unroll
            for (int j = 0; j < 8; ++j)
                xv[j] = ldS(x, ((long)b * CC + kbase + j) * NN + n, f32);
            uint4 au;
            au.x = pack2bf(xv[0], xv[1]); au.y = pack2bf(xv[2], xv[3]);
            au.z = pack2bf(xv[4], xv[5]); au.w = pack2bf(xv[6], xv[7]);
            short8 a = *reinterpret_cast<short8*>(&au);
            #pragma unroll
            for (int wi = 0; wi < 3; ++wi)
                #pragma unroll
                for (int ct = 0; ct < 4; ++ct) {
                    short8 bfr = *reinterpret_cast<const short8*>(
                        &Wl[wi][ct * 16 + l15][ks * 32 + quad * 8]);
                    acc[wi][ct] = __builtin_amdgcn_mfma_f32_16x16x32_bf16(
                        a, bfr, acc[wi][ct], 0, 0, 0);
                }
        }
        __syncthreads();
    }

    // D: row = quad*4+r (n-local), col = l15 (c-local within ct tile)
    // fxF / gxF epilogue
    #pragma unroll
    for (int wi = 0; wi < 2; ++wi) {
        unsigned short* __restrict__ dstF = (wi == 0) ? fxF : gxF;
        const int nloc = 16 * wv + quad * 4;
        #pragma unroll
        for (int ct = 0; ct < 4; ++ct)
            #pragma unroll
            for (int r = 0; r < 4; ++r) {
                int nn = n0 + nloc + r;
                size_t off = (((size_t)(b * 128 + (nn >> 5)) * 4 + ct) * 64
                              + (l15 >> 3) * 32 + (nn & 31)) * 8 + (l15 & 7);
                dstF[off] = f2bf(acc[wi][ct][r]);
            }
    }
    // hxF epilogue
    {
        const int tile = (n0 + 16 * wv) >> 5;
        const int ich  = wv & 1;
        const int ksub = quad >> 1;
        const int ebase = (quad & 1) * 4;
        #pragma unroll
        for (int ct = 0; ct < 4; ++ct) {
            int part = ct >> 1;
            int lloc = ksub * 32 + (ct & 1) * 16 + l15;
            size_t off = ((((size_t)(b * 128 + tile) * 2 + ich) * 2 + part) * 64
                          + lloc) * 8 + ebase;
            uint2 o;
            o.x = pack2bf(acc[2][ct][0], acc[2][ct][1]);
            o.y = pack2bf(acc[2][ct][2], acc[2][ct][3]);
            *reinterpret_cast<uint2*>(&hxF[off]) = o;
        }
    }
}

// ---------------------------------------------------------------------------
// rowstats: rl[b,i] += sum_j 2^(S'_ij)  (fx carries log2e). 4 waves, wave
// owns 32 i-rows, sweeps 512 j; lane-linear frag loads, no LDS/barriers.
// ---------------------------------------------------------------------------
__global__ __launch_bounds__(256, 4) void rowstats_kernel(
    const unsigned short* __restrict__ fxF, const unsigned short* __restrict__ gxF,
    float* __restrict__ rl)
{
    const int t = threadIdx.x;
    const int w = t >> 6, l = t & 63, l31 = l & 31, hi = l >> 5;
    const int b = blockIdx.z;
    const int i0 = blockIdx.x * 128 + w * 32;
    const int jbase = blockIdx.y * (NN / 8);

    const unsigned short* fA = fxF + ((size_t)(b * 128 + (i0 >> 5))) * 2048 + (size_t)l * 8;
    uint4 af[4];
    #pragma unroll
    for (int kc = 0; kc < 4; ++kc)
        af[kc] = *reinterpret_cast<const uint4*>(fA + kc * 512);

    const unsigned short* gB = gxF + ((size_t)(b * 128 + (jbase >> 5))) * 2048 + (size_t)l * 8;

    float suml[16];
    #pragma unroll
    for (int r = 0; r < 16; ++r) suml[r] = 0.f;

    uint4 bf0[4], bf1[4];
    auto loadB = [&](uint4* bf, int jt) {
        const unsigned short* p = gB + (size_t)jt * 2048;
        #pragma unroll
        for (int kc = 0; kc < 4; ++kc)
            bf[kc] = *reinterpret_cast<const uint4*>(p + kc * 512);
    };
    auto bodyR = [&](uint4* bf) {
        floatx16 s = zero16();
        #pragma unroll
        for (int kc = 0; kc < 4; ++kc)
            s = MFMA32(as_s8(af[kc]), as_s8(bf[kc]), s);
        #pragma unroll
        for (int r = 0; r < 16; ++r) suml[r] += exp2a(s[r]);
    };

    loadB(bf0, 0);
    for (int jt = 0; jt < 16; jt += 2) {
        loadB(bf1, jt + 1);
        bodyR(bf0);
        if (jt + 2 < 16) loadB(bf0, jt + 2);
        bodyR(bf1);
    }

    #pragma unroll
    for (int r = 0; r < 16; ++r) {
        float v = suml[r];
        v += __shfl_xor(v, 1);
        v += __shfl_xor(v, 2);
        v += __shfl_xor(v, 4);
        v += __shfl_xor(v, 8);
        v += __shfl_xor(v, 16);
        suml[r] = v;
    }
    if (l31 == 0) {
        #pragma unroll
        for (int r = 0; r < 16; ++r) {
            int row = (r & 3) + 8 * (r >> 2) + 4 * hi;
            atomicAdd(&rl[(size_t)b * NN + i0 + row], suml[r]);
        }
    }
}

// ---------------------------------------------------------------------------
// scalehx (in-place): hxF *= 1/rl[i] per element (folds softmax denom into V).
// hxF chunk idx -> (l=idx&63, r=idx>>6): part=r&1, ich=(r>>1)&1,
// tile=(r>>2)&127, b=r>>9; i0 = tile*32+ich*16+(l>>5)*8; elements e=0..7 -> i0+e.
// ---------------------------------------------------------------------------
__global__ __launch_bounds__(256) void scalehx_kernel(
    const float* __restrict__ rl, unsigned short* __restrict__ hxF)
{
    const int idx = blockIdx.x * 256 + threadIdx.x;   // 0..131071
    const int l = idx & 63;
    const int r = idx >> 6;
    const int ich = (r >> 1) & 1;
    const int tile = (r >> 2) & 127;
    const int b = r >> 9;
    const int i0 = tile * 32 + ich * 16 + (l >> 5) * 8;
    const float* rp = rl + (size_t)b * NN + i0;
    float4 ra = *reinterpret_cast<const float4*>(rp);
    float4 rb = *reinterpret_cast<const float4*>(rp + 4);
    uint4 v = *reinterpret_cast<uint4*>(hxF + (size_t)idx * 8);
    uint4 ov;
    ov.x = pack2bf(bf16lo(v.x) * rcpf(ra.x), bf16hi(v.x) * rcpf(ra.y));
    ov.y = pack2bf(bf16lo(v.y) * rcpf(ra.z), bf16hi(v.y) * rcpf(ra.w));
    ov.z = pack2bf(bf16lo(v.z) * rcpf(rb.x), bf16hi(v.z) * rcpf(rb.y));
    ov.w = pack2bf(bf16lo(v.w) * rcpf(rb.z), bf16hi(v.w) * rcpf(rb.w));
    *reinterpret_cast<uint4*>(hxF + (size_t)idx * 8) = ov;
}

// ---------------------------------------------------------------------------
// pv: opF[isb][n=j][cp=c] = sum_i 2^(S'_ij) * (hx/l)[c,i] over the block's
// i quarter-range. 4 waves = 2 igrp x 2 jgrp; per wave: j-sub 32, full c,
// 16 i-tiles. acc = 2 floatx16 (c halves). All loads lane-linear. <=128
// regs -> 4 waves/SIMD. LDS-reduce igrp pairs; epilogue writes outproj's
// 16x16x32 A-frag layout (plain fp32 stores, no global atomics).
// ---------------------------------------------------------------------------
__global__ __launch_bounds__(256, 4) void pv_kernel(
    const unsigned short* __restrict__ fxF, const unsigned short* __restrict__ gxF,
    const unsigned short* __restrict__ hxF,
    float* __restrict__ opF0, float* __restrict__ opF1,
    float* __restrict__ opF2, float* __restrict__ opF3)
{
    const int t = threadIdx.x;
    const int w = t >> 6, l = t & 63, l31 = l & 31, hi = l >> 5;
    const int igrp = w >> 1, jgrp = w & 1;
    const int b = blockIdx.z;
    const int j0 = blockIdx.x * 64;
    const int isb = blockIdx.y;
    const int tbase = isb * 32 + igrp * 16;    // first 32-row i-tile index

    __shared__ float red[64 * 64];

    // hoist gx B-frags for this wave's j-sub (32 rows)
    uint4 qf[4];
    {
        const unsigned short* gq =
            gxF + ((size_t)(b * 128 + (j0 >> 5) + jgrp)) * 2048 + (size_t)l * 8;
        #pragma unroll
        for (int kc = 0; kc < 4; ++kc)
            qf[kc] = *reinterpret_cast<const uint4*>(gq + kc * 512);
    }

    floatx16 acc0 = zero16(), acc1 = zero16();

    const unsigned short* fb = fxF + ((size_t)(b * 128 + tbase)) * 2048 + (size_t)l * 8;
    const unsigned short* vb = hxF + ((size_t)(b * 128 + tbase)) * 2048 + (size_t)l * 8;

    #pragma unroll 2
    for (int it = 0; it < 16; ++it) {
        const unsigned short* fp = fb + (size_t)it * 2048;
        const unsigned short* vp = vb + (size_t)it * 2048;
        uint4 af[4], vf[4];
        #pragma unroll
        for (int kc = 0; kc < 4; ++kc)
            af[kc] = *reinterpret_cast<const uint4*>(fp + kc * 512);
        vf[0] = *reinterpret_cast<const uint4*>(vp);           // ich0 part0
        vf[1] = *reinterpret_cast<const uint4*>(vp + 1024);    // ich1 part0
        vf[2] = *reinterpret_cast<const uint4*>(vp + 512);     // ich0 part1
        vf[3] = *reinterpret_cast<const uint4*>(vp + 1536);    // ich1 part1

        floatx16 s = zero16();
        #pragma unroll
        for (int kc = 0; kc < 4; ++kc)
            s = MFMA32(as_s8(af[kc]), as_s8(qf[kc]), s);

        float e[16];
        #pragma unroll
        for (int r = 0; r < 16; ++r) e[r] = exp2a(s[r]);

        unsigned u0 = cvtpk_bf16(e[0], e[1]);
        unsigned u1 = cvtpk_bf16(e[2], e[3]);
        unsigned u2 = cvtpk_bf16(e[4], e[5]);
        unsigned u3 = cvtpk_bf16(e[6], e[7]);
        pl32swap(u0, u2);
        pl32swap(u1, u3);
        uint4 pa0 = make_uint4(u0, u1, u2, u3);      // P k-chunk i 0..15
        unsigned u4 = cvtpk_bf16(e[8], e[9]);
        unsigned u5 = cvtpk_bf16(e[10], e[11]);
        unsigned u6 = cvtpk_bf16(e[12], e[13]);
        unsigned u7 = cvtpk_bf16(e[14], e[15]);
        pl32swap(u4, u6);
        pl32swap(u5, u7);
        uint4 pa1 = make_uint4(u4, u5, u6, u7);      // P k-chunk i 16..31

        acc0 = MFMA32(as_s8(pa0), as_s8(vf[0]), acc0);
        acc0 = MFMA32(as_s8(pa1), as_s8(vf[1]), acc0);
        acc1 = MFMA32(as_s8(pa0), as_s8(vf[2]), acc1);
        acc1 = MFMA32(as_s8(pa1), as_s8(vf[3]), acc1);
    }

    // block reduce (igrp pairs) into red[j-local][c]
    #pragma unroll
    for (int q = 0; q < 4; ++q)
        *reinterpret_cast<float4*>(&red[(q * 256 + t) * 4]) =
            make_float4(0.f, 0.f, 0.f, 0.f);
    __syncthreads();
    #pragma unroll
    for (int r = 0; r < 16; ++r) {
        int row = jgrp * 32 + (r & 3) + 8 * (r >> 2) + 4 * hi;
        atomicAdd(&red[row * 64 + l31],      acc0[r]);
        atomicAdd(&red[row * 64 + 32 + l31], acc1[r]);
    }
    __syncthreads();

    // write outproj A-frag layout
    float* __restrict__ dst = (isb == 0) ? opF0 : ((isb == 1) ? opF1 : ((isb == 2) ? opF2 : opF3));
    #pragma unroll
    for (int q = 0; q < 4; ++q) {
        int idx = q * 256 + t;                 // 0..1023
        int e2  = idx & 1;
        int ll  = (idx >> 1) & 63;
        int ks  = (idx >> 7) & 1;
        int ntl = idx >> 8;
        int jloc = ntl * 16 + (ll & 15);
        int cp   = ks * 32 + ((ll >> 4) << 3) + e2 * 4;
        float4 v = *reinterpret_cast<const float4*>(&red[jloc * 64 + cp]);
        size_t off = (((size_t)(b * 256 + (j0 >> 4) + ntl) * 2 + ks) * 64 + ll) * 8 + e2 * 4;
        *reinterpret_cast<float4*>(dst + off) = v;
    }
}

// ---------------------------------------------------------------------------
// outproj (MFMA): y^T[n][co] = scale * sum_cp (sum4 opF)[n][cp] Wv^T[cp][co] + x.
// A-frags lane-linear from the 4 opF partials, summed in registers.
// ---------------------------------------------------------------------------
__global__ __launch_bounds__(256) void outproj_kernel(
    const void* __restrict__ x,
    const void* __restrict__ Wv,
    const void* __restrict__ gamma,
    const int* __restrict__ dflag,
    const float* __restrict__ sig,
    const float* __restrict__ opF0, const float* __restrict__ opF1,
    const float* __restrict__ opF2, const float* __restrict__ opF3,
    void* __restrict__ y)
{
    const int f32 = *dflag;
    const int n0     = blockIdx.x * 64;
    const int cobase = blockIdx.y * 128;
    const int b      = blockIdx.z;
    const int t = threadIdx.x;
    const int wv = t >> 6, l = t & 63, l15 = l & 15, quad = l >> 4;
    const float scale = ldS(gamma, 0, f32) * sig[3];

    floatx4 acc[4][2];
    #pragma unroll
    for (int ns = 0; ns < 4; ++ns)
        #pragma unroll
        for (int ct = 0; ct < 2; ++ct) acc[ns][ct] = (floatx4){0.f, 0.f, 0.f, 0.f};

    #pragma unroll
    for (int ks = 0; ks < 2; ++ks) {
        short8 a[4];
        #pragma unroll
        for (int ns = 0; ns < 4; ++ns) {
            size_t fo = (((size_t)(b * 256 + (n0 >> 4) + ns) * 2 + ks) * 64 + l) * 8;
            float4 s0 = *reinterpret_cast<const float4*>(opF0 + fo);
            float4 s1 = *reinterpret_cast<const float4*>(opF1 + fo);
            float4 s2 = *reinterpret_cast<const float4*>(opF2 + fo);
            float4 s3 = *reinterpret_cast<const float4*>(opF3 + fo);
            float4 t0 = *reinterpret_cast<const float4*>(opF0 + fo + 4);
            float4 t1 = *reinterpret_cast<const float4*>(opF1 + fo + 4);
            float4 t2 = *reinterpret_cast<const float4*>(opF2 + fo + 4);
            float4 t3 = *reinterpret_cast<const float4*>(opF3 + fo + 4);
            float v0 = s0.x + s1.x + s2.x + s3.x;
            float v1 = s0.y + s1.y + s2.y + s3.y;
            float v2 = s0.z + s1.z + s2.z + s3.z;
            float v3 = s0.w + s1.w + s2.w + s3.w;
            float v4 = t0.x + t1.x + t2.x + t3.x;
            float v5 = t0.y + t1.y + t2.y + t3.y;
            float v6 = t0.z + t1.z + t2.z + t3.z;
            float v7 = t0.w + t1.w + t2.w + t3.w;
            uint4 au;
            au.x = pack2bf(v0, v1); au.y = pack2bf(v2, v3);
            au.z = pack2bf(v4, v5); au.w = pack2bf(v6, v7);
            a[ns] = *reinterpret_cast<short8*>(&au);
        }
        const int kb = ks * 32 + quad * 8;
        #pragma unroll
        for (int ct = 0; ct < 2; ++ct) {
            const int co = cobase + 32 * wv + 16 * ct + l15;
            short8 bfr = frag8(Wv, (long)co * CP + kb, f32);
            #pragma unroll
            for (int ns = 0; ns < 4; ++ns)
                acc[ns][ct] = __builtin_amdgcn_mfma_f32_16x16x32_bf16(
                    a[ns], bfr, acc[ns][ct], 0, 0, 0);
        }
    }

    #pragma unroll
    for (int ns = 0; ns < 4; ++ns)
        #pragma unroll
        for (int ct = 0; ct < 2; ++ct) {
            const int co = cobase + 32 * wv + 16 * ct + l15;
            const long base = ((long)b * CC + co) * NN + n0 + 16 * ns + quad * 4;
            float4 xv = ld4(x, base, f32);
            float o0 = fmaf(scale, acc[ns][ct][0], xv.x);
            float o1 = fmaf(scale, acc[ns][ct][1], xv.y);
            float o2 = fmaf(scale, acc[ns][ct][2], xv.z);
            float o3 = fmaf(scale, acc[ns][ct][3], xv.w);
            if (f32) {
                *reinterpret_cast<float4*>((float*)y + base) = make_float4(o0, o1, o2, o3);
            } else {
                uint2 o;
                o.x = pack2bf(o0, o1);
                o.y = pack2bf(o2, o3);
                *reinterpret_cast<uint2*>((unsigned short*)y + base) = o;
            }
        }
}

// ---------------------------------------------------------------------------
extern "C" void kernel_launch(void* const* d_in, const int* in_sizes, int n_in,
                              void* d_out, int out_size, void* d_ws, size_t ws_size,
                              hipStream_t stream)
{
    const void* x  = d_in[0];
    const void* Wf = d_in[1];
    const void* Wg = d_in[2];
    const void* Wh = d_in[3];
    const void* Wv = d_in[4];
    const void* uf = d_in[5];
    const void* ug = d_in[6];
    const void* uh = d_in[7];
    const void* uv = d_in[8];
    const void* gm = d_in[9];

    // ws: dfl | sig | rl (64KB) | opF0..3 (4x4MB) | fxF | gxF | hxF (2MB bf16 each)
    char* base = (char*)d_ws;
    int*   dfl = (int*)(base);
    float* sig = (float*)(base + 512);
    float* rl  = (float*)(base + 1024);
    float* opF0 = (float*)(base + 1024 + 65536);
    float* opF1 = opF0 + (size_t)NB * NN * CP;
    float* opF2 = opF1 + (size_t)NB * NN * CP;
    float* opF3 = opF2 + (size_t)NB * NN * CP;
    unsigned short* fxF = (unsigned short*)(opF3 + (size_t)NB * NN * CP);
    unsigned short* gxF = fxF + (size_t)NB * CP * NN;
    unsigned short* hxF = gxF + (size_t)NB * CP * NN;

    hipMemsetAsync(rl, 0, (size_t)NB * NN * sizeof(float), stream);

    hipLaunchKernelGGL(detect_kernel, dim3(1), dim3(256), 0, stream,
                       (const unsigned*)x, dfl);
    hipLaunchKernelGGL(sigma_kernel, dim3(4), dim3(512), 0, stream,
                       Wf, Wg, Wh, Wv, uf, ug, uh, uv, dfl, sig);
    hipLaunchKernelGGL(proj_kernel, dim3(NN / 64, NB), dim3(256), 0, stream,
                       x, Wf, Wg, Wh, dfl, sig, fxF, gxF, hxF);
    hipLaunchKernelGGL(rowstats_kernel, dim3(NN / 128, 8, NB), dim3(256), 0, stream,
                       fxF, gxF, rl);
    hipLaunchKernelGGL(scalehx_kernel, dim3((NB * CP * NN / 8) / 256), dim3(256), 0, stream,
                       rl, hxF);
    hipLaunchKernelGGL(pv_kernel, dim3(NN / 64, 4, NB), dim3(256), 0, stream,
                       fxF, gxF, hxF, opF0, opF1, opF2, opF3);
    hipLaunchKernelGGL(outproj_kernel, dim3(NN / 64, CC / 128, NB), dim3(256), 0, stream,
                       x, Wv, gm, dfl, sig, opF0, opF1, opF2, opF3, d_out);
}

// Round 4
// 226.164 us; speedup vs baseline: 1.2950x; 1.2950x over previous
//
#include <hip/hip_runtime.h>

// SAGAN self-attention, B=4, C=512, Cp=64, N=64*64=4096. fp32 in/out
// (runtime-detected). Pipeline: detect -> xpose (x -> xTF fragment-order
// bf16, LDS transpose) -> sigma -> wprep (sigma-scaled W -> WF fragment
// order) -> proj (pure streaming MFMA, no LDS/barriers, lane-linear loads,
// swap-based frag-order epilogue) -> rowstats -> scalehx -> pv -> outproj.
// All inter-stage tensors in MFMA fragment-order layouts.
//
// xTF layout (32-row n-tiles, k=C): off(b,nt,kc,l,e)=(((b*128+nt)*32+kc)*64+l)*8+e
//   content: (n = nt*32 + (l&31), c = kc*16 + (l>>5)*8 + e), kc 0..31
// WF  layout: off(wi,cpt,kc,l,e)=(((wi*2+cpt)*32+kc)*64+l)*8+e
//   content: (cp = cpt*32 + (l&31), c = kc*16 + (l>>5)*8 + e) * sig (wi0: *log2e)
// fxF/gxF layout (k=Cp): off(b,tile,kc,l,e) = (((b*128+tile)*4+kc)*64+l)*8+e
//   content: (n = tile*32 + (l&31), c = kc*16 + (l>>5)*8 + e)
// hxF layout (PV B-frag): off(b,tile,ich,part,l,e)=((((b*128+tile)*2+ich)*2+part)*64+l)*8+e
//   content: (c = part*32 + (l&31), i = tile*32 + ich*16 + (l>>5)*8 + e)
// opF layout (outproj A-frag): off(b,ntl,ks,l,e)=(((b*256+ntl)*2+ks)*64+l)*8+e
//   content: (n = ntl*16 + (l&15), cp = ks*32 + (l>>4)*8 + e)

#define NB 4
#define CC 512
#define CP 64
#define NN 4096
#define L2E 1.4426950408889634f

typedef __attribute__((ext_vector_type(8))) short short8;
typedef __attribute__((ext_vector_type(4))) float floatx4;
typedef __attribute__((ext_vector_type(16))) float floatx16;

#define MFMA32(A, B, C) __builtin_amdgcn_mfma_f32_32x32x16_bf16((A), (B), (C), 0, 0, 0)

__device__ __forceinline__ float bf2f_u(unsigned short h) {
    return __uint_as_float((unsigned)h << 16);
}
__device__ __forceinline__ float bf16lo(unsigned v) { return __uint_as_float(v << 16); }
__device__ __forceinline__ float bf16hi(unsigned v) { return __uint_as_float(v & 0xffff0000u); }
__device__ __forceinline__ unsigned short f2bf(float f) {
    unsigned u = __float_as_uint(f);
    u += 0x7fffu + ((u >> 16) & 1u);   // RNE
    return (unsigned short)(u >> 16);
}
__device__ __forceinline__ unsigned pack2bf(float a, float b) {
    return (unsigned)f2bf(a) | ((unsigned)f2bf(b) << 16);
}
__device__ __forceinline__ float ldS(const void* p, long i, int f32) {
    return f32 ? ((const float*)p)[i] : bf2f_u(((const unsigned short*)p)[i]);
}
__device__ __forceinline__ float4 ld4(const void* p, long i, int f32) {
    if (f32) return *reinterpret_cast<const float4*>((const float*)p + i);
    uint2 v = *reinterpret_cast<const uint2*>((const unsigned short*)p + i);
    return make_float4(bf16lo(v.x), bf16hi(v.x), bf16lo(v.y), bf16hi(v.y));
}
__device__ __forceinline__ short8 frag8(const void* p, long i, int f32) {
    uint4 au;
    if (f32) {
        float4 v0 = *reinterpret_cast<const float4*>((const float*)p + i);
        float4 v1 = *reinterpret_cast<const float4*>((const float*)p + i + 4);
        au.x = pack2bf(v0.x, v0.y); au.y = pack2bf(v0.z, v0.w);
        au.z = pack2bf(v1.x, v1.y); au.w = pack2bf(v1.z, v1.w);
    } else {
        au = *reinterpret_cast<const uint4*>((const unsigned short*)p + i);
    }
    return *reinterpret_cast<short8*>(&au);
}
__device__ __forceinline__ short8 as_s8(uint4 v) { return *reinterpret_cast<short8*>(&v); }
__device__ __forceinline__ floatx16 zero16() {
    floatx16 z;
    #pragma unroll
    for (int i = 0; i < 16; ++i) z[i] = 0.f;
    return z;
}
__device__ __forceinline__ unsigned cvtpk_bf16(float a, float b) {
    unsigned r;
    asm("v_cvt_pk_bf16_f32 %0, %1, %2" : "=v"(r) : "v"(a), "v"(b));
    return r;
}
__device__ __forceinline__ void pl32swap(unsigned &a, unsigned &b) {
    asm("v_permlane32_swap_b32 %0, %1" : "+v"(a), "+v"(b));
}
__device__ __forceinline__ float rcpf(float x) {
    float r;
    asm("v_rcp_f32 %0, %1" : "=v"(r) : "v"(x));
    return r;
}
__device__ __forceinline__ float exp2a(float x) {   // 2^x
    float r;
    asm("v_exp_f32 %0, %1" : "=v"(r) : "v"(x));
    return r;
}

// ---------------------------------------------------------------------------
// dtype detector: 1 if fp32, 0 if bf16.
// ---------------------------------------------------------------------------
__global__ __launch_bounds__(256) void detect_kernel(
    const unsigned* __restrict__ x, int* __restrict__ flag)
{
    __shared__ int red[256];
    const int t = threadIdx.x;
    int bad = 0;
    for (int i = t; i < 4096; i += 256) {
        unsigned w = x[i];
        float f0 = __uint_as_float(w << 16);
        float f1 = __uint_as_float(w & 0xffff0000u);
        float a0 = fabsf(f0), a1 = fabsf(f1);
        if (!(a0 <= 1e3f) || (f0 != 0.f && a0 < 1e-20f)) bad++;
        if (!(a1 <= 1e3f) || (f1 != 0.f && a1 < 1e-20f)) bad++;
    }
    red[t] = bad;
    __syncthreads();
    for (int s = 128; s > 0; s >>= 1) { if (t < s) red[t] += red[t + s]; __syncthreads(); }
    if (t == 0) *flag = (red[0] > 64) ? 1 : 0;
}

// ---------------------------------------------------------------------------
// xpose: x[b][c][n] -> xTF fragment-order bf16. Per block: one 32-n tile,
// full C. LDS transpose per 64-c slab; coalesced global loads (2x128B per
// instr), dwordx4 lane-linear stores.
// ---------------------------------------------------------------------------
__global__ __launch_bounds__(256) void xpose_kernel(
    const void* __restrict__ x, const int* __restrict__ dflag,
    unsigned short* __restrict__ xTF)
{
    const int f32 = *dflag;
    const int nt = blockIdx.x;      // 0..127
    const int b  = blockIdx.y;
    const int n0 = nt * 32;
    const int t = threadIdx.x;
    __shared__ unsigned short xl[32][72];   // [n][c], pad 8 -> 16B-aligned rows

    const int n_l = t & 31, cg8 = ((t >> 5) & 7) * 8;
    const int q = t >> 6, lo = t & 63;

    for (int slab = 0; slab < 8; ++slab) {
        const int cs = slab * 64;
        float v[8];
        #pragma unroll
        for (int j = 0; j < 8; ++j)
            v[j] = ldS(x, ((long)b * CC + cs + cg8 + j) * NN + n0 + n_l, f32);
        if (slab) __syncthreads();    // WAR: previous readers done
        unsigned* row = reinterpret_cast<unsigned*>(&xl[n_l][cg8]);
        row[0] = pack2bf(v[0], v[1]);
        row[1] = pack2bf(v[2], v[3]);
        row[2] = pack2bf(v[4], v[5]);
        row[3] = pack2bf(v[6], v[7]);
        __syncthreads();
        const int cb = q * 16 + ((lo >> 5) << 3);
        uint4 val = *reinterpret_cast<const uint4*>(&xl[lo & 31][cb]);
        size_t off = (((size_t)(b * 128 + nt) * 32) + slab * 4 + q) * 512 + (size_t)lo * 8;
        *reinterpret_cast<uint4*>(xTF + off) = val;
    }
}

// ---------------------------------------------------------------------------
// sigma: a = W^T u; sigma = ||a||^2 / (||a||+eps); writes 1/sigma.
// ---------------------------------------------------------------------------
__global__ __launch_bounds__(512) void sigma_kernel(
    const void* __restrict__ Wf, const void* __restrict__ Wg,
    const void* __restrict__ Wh, const void* __restrict__ Wv,
    const void* __restrict__ uf, const void* __restrict__ ug,
    const void* __restrict__ uh, const void* __restrict__ uv,
    const int* __restrict__ dflag, float* __restrict__ sig)
{
    const int f32 = *dflag;
    const int w = blockIdx.x;
    const void* W;
    const void* u;
    if (w == 0)      { W = Wf; u = uf; }
    else if (w == 1) { W = Wg; u = ug; }
    else if (w == 2) { W = Wh; u = uh; }
    else             { W = Wv; u = uv; }

    __shared__ float us[512];
    __shared__ float red[512];
    const int t = threadIdx.x;
    float S;

    if (w < 3) {
        if (t < 64) us[t] = ldS(u, t, f32);
        __syncthreads();
        float a = 0.f;
        #pragma unroll
        for (int i = 0; i < 64; ++i)
            a = fmaf(ldS(W, (long)i * 512 + t, f32), us[i], a);
        red[t] = a * a;
        __syncthreads();
        #pragma unroll
        for (int s = 256; s > 0; s >>= 1) {
            if (t < s) red[t] += red[t + s];
            __syncthreads();
        }
        S = red[0];
    } else {
        us[t] = ldS(u, t, f32);
        __syncthreads();
        const int g = t >> 6, c = t & 63;
        float a = 0.f;
        #pragma unroll
        for (int k = 0; k < 64; ++k) {
            int i = g + k * 8;
            a = fmaf(ldS(W, (long)i * 64 + c, f32), us[i], a);
        }
        red[t] = a;
        __syncthreads();
        #pragma unroll
        for (int s = 256; s >= 64; s >>= 1) {
            if (t < s) red[t] += red[t + s];
            __syncthreads();
        }
        float ac = (t < 64) ? red[t] : 0.f;
        __syncthreads();
        red[t] = ac * ac;
        __syncthreads();
        #pragma unroll
        for (int s = 256; s > 0; s >>= 1) {
            if (t < s) red[t] += red[t + s];
            __syncthreads();
        }
        S = red[0];
    }
    if (t == 0) sig[w] = (sqrtf(S) + 1e-12f) / S;
}

// ---------------------------------------------------------------------------
// wprep: WF[wi][cpt][kc][l][e] = W[cp][c] * sig[wi] (*log2e for wi=0), bf16.
// grid 48 x 256; one 16B chunk per thread; lane-linear stores.
// ---------------------------------------------------------------------------
__global__ __launch_bounds__(256) void wprep_kernel(
    const void* __restrict__ Wf, const void* __restrict__ Wg,
    const void* __restrict__ Wh,
    const int* __restrict__ dflag, const float* __restrict__ sig,
    unsigned short* __restrict__ WF)
{
    const int f32 = *dflag;
    const int idx = blockIdx.x * 256 + threadIdx.x;   // 0..12287
    const int l   = idx & 63;
    const int kc  = (idx >> 6) & 31;
    const int cpt = (idx >> 11) & 1;
    const int wi  = idx >> 12;
    const void* W = (wi == 0) ? Wf : ((wi == 1) ? Wg : Wh);
    const float sc = sig[wi] * (wi == 0 ? L2E : 1.f);
    const int cp = cpt * 32 + (l & 31);
    const int c  = kc * 16 + ((l >> 5) << 3);
    const long base = (long)cp * CC + c;
    float a0 = ldS(W, base + 0, f32) * sc, a1 = ldS(W, base + 1, f32) * sc;
    float a2 = ldS(W, base + 2, f32) * sc, a3 = ldS(W, base + 3, f32) * sc;
    float a4 = ldS(W, base + 4, f32) * sc, a5 = ldS(W, base + 5, f32) * sc;
    float a6 = ldS(W, base + 6, f32) * sc, a7 = ldS(W, base + 7, f32) * sc;
    uint4 o;
    o.x = pack2bf(a0, a1); o.y = pack2bf(a2, a3);
    o.z = pack2bf(a4, a5); o.w = pack2bf(a6, a7);
    *reinterpret_cast<uint4*>(WF + (size_t)idx * 8) = o;
}

// ---------------------------------------------------------------------------
// proj (streaming MFMA): out[n][cp] = sum_c xT[n][c] * Wsc[cp][c] for the
// block's (wi,cpt). No LDS, no barriers, all loads lane-linear. Dual parity
// accumulators break the MFMA dep chain. Epilogue: cvt_pk + permlane32_swap
// -> two lane-linear dwordx4 stores into fxF/gxF (A=W orient, lanes=n) or
// hxF (A=xT orient, lanes=c).
// ---------------------------------------------------------------------------
__global__ __launch_bounds__(256, 4) void proj_kernel(
    const unsigned short* __restrict__ xTF,
    const unsigned short* __restrict__ WF,
    unsigned short* __restrict__ fxF, unsigned short* __restrict__ gxF,
    unsigned short* __restrict__ hxF)
{
    const int t = threadIdx.x;
    const int w = t >> 6, l = t & 63;
    const int b  = blockIdx.y;
    const int zc = blockIdx.z;                 // wi*2 + cpt
    const int wi = zc >> 1, cpt = zc & 1;
    const int nt = blockIdx.x * 4 + w;

    const unsigned short* xb = xTF + ((size_t)(b * 128 + nt) * 32) * 512 + (size_t)l * 8;
    const unsigned short* wb = WF + ((size_t)zc * 32) * 512 + (size_t)l * 8;

    floatx16 accE = zero16(), accO = zero16();
    uint4 x0 = *reinterpret_cast<const uint4*>(xb);
    uint4 w0 = *reinterpret_cast<const uint4*>(wb);
    uint4 x1, w1;

    if (wi == 2) {
        for (int kc = 0; kc < 32; kc += 2) {
            x1 = *reinterpret_cast<const uint4*>(xb + (kc + 1) * 512);
            w1 = *reinterpret_cast<const uint4*>(wb + (kc + 1) * 512);
            accE = MFMA32(as_s8(x0), as_s8(w0), accE);
            if (kc + 2 < 32) {
                x0 = *reinterpret_cast<const uint4*>(xb + (kc + 2) * 512);
                w0 = *reinterpret_cast<const uint4*>(wb + (kc + 2) * 512);
            }
            accO = MFMA32(as_s8(x1), as_s8(w1), accO);
        }
    } else {
        for (int kc = 0; kc < 32; kc += 2) {
            x1 = *reinterpret_cast<const uint4*>(xb + (kc + 1) * 512);
            w1 = *reinterpret_cast<const uint4*>(wb + (kc + 1) * 512);
            accE = MFMA32(as_s8(w0), as_s8(x0), accE);
            if (kc + 2 < 32) {
                x0 = *reinterpret_cast<const uint4*>(xb + (kc + 2) * 512);
                w0 = *reinterpret_cast<const uint4*>(wb + (kc + 2) * 512);
            }
            accO = MFMA32(as_s8(w1), as_s8(x1), accO);
        }
    }

    float a[16];
    #pragma unroll
    for (int i = 0; i < 16; ++i) a[i] = accE[i] + accO[i];

    if (wi < 2) {
        // acc: col(lane&31)=n-local, reg=cp-local ((r&3)+8*(r>>2)+4*hi)
        unsigned short* __restrict__ dstF = (wi == 0) ? fxF : gxF;
        #pragma unroll
        for (int kcl = 0; kcl < 2; ++kcl) {
            const int r8 = kcl * 8;
            unsigned u0 = cvtpk_bf16(a[r8 + 0], a[r8 + 1]);
            unsigned u1 = cvtpk_bf16(a[r8 + 2], a[r8 + 3]);
            unsigned u2 = cvtpk_bf16(a[r8 + 4], a[r8 + 5]);
            unsigned u3 = cvtpk_bf16(a[r8 + 6], a[r8 + 7]);
            pl32swap(u0, u2);
            pl32swap(u1, u3);
            uint4 o = make_uint4(u0, u1, u2, u3);
            size_t off = (((size_t)(b * 128 + nt) * 4) + cpt * 2 + kcl) * 512 + (size_t)l * 8;
            *reinterpret_cast<uint4*>(dstF + off) = o;
        }
    } else {
        // acc: col(lane&31)=cp-local, reg=n-local
        #pragma unroll
        for (int ich = 0; ich < 2; ++ich) {
            const int r8 = ich * 8;
            unsigned u0 = cvtpk_bf16(a[r8 + 0], a[r8 + 1]);
            unsigned u1 = cvtpk_bf16(a[r8 + 2], a[r8 + 3]);
            unsigned u2 = cvtpk_bf16(a[r8 + 4], a[r8 + 5]);
            unsigned u3 = cvtpk_bf16(a[r8 + 6], a[r8 + 7]);
            pl32swap(u0, u2);
            pl32swap(u1, u3);
            uint4 o = make_uint4(u0, u1, u2, u3);
            size_t off = ((((size_t)(b * 128 + nt) * 2 + ich) * 2) + cpt) * 512 + (size_t)l * 8;
            *reinterpret_cast<uint4*>(hxF + off) = o;
        }
    }
}

// ---------------------------------------------------------------------------
// rowstats: rl[b,i] += sum_j 2^(S'_ij)  (fx carries log2e). 4 waves, wave
// owns 32 i-rows, sweeps 512 j; lane-linear frag loads, no LDS/barriers.
// ---------------------------------------------------------------------------
__global__ __launch_bounds__(256, 4) void rowstats_kernel(
    const unsigned short* __restrict__ fxF, const unsigned short* __restrict__ gxF,
    float* __restrict__ rl)
{
    const int t = threadIdx.x;
    const int w = t >> 6, l = t & 63, l31 = l & 31, hi = l >> 5;
    const int b = blockIdx.z;
    const int i0 = blockIdx.x * 128 + w * 32;
    const int jbase = blockIdx.y * (NN / 8);

    const unsigned short* fA = fxF + ((size_t)(b * 128 + (i0 >> 5))) * 2048 + (size_t)l * 8;
    uint4 af[4];
    #pragma unroll
    for (int kc = 0; kc < 4; ++kc)
        af[kc] = *reinterpret_cast<const uint4*>(fA + kc * 512);

    const unsigned short* gB = gxF + ((size_t)(b * 128 + (jbase >> 5))) * 2048 + (size_t)l * 8;

    float suml[16];
    #pragma unroll
    for (int r = 0; r < 16; ++r) suml[r] = 0.f;

    uint4 bf0[4], bf1[4];
    auto loadB = [&](uint4* bf, int jt) {
        const unsigned short* p = gB + (size_t)jt * 2048;
        #pragma unroll
        for (int kc = 0; kc < 4; ++kc)
            bf[kc] = *reinterpret_cast<const uint4*>(p + kc * 512);
    };
    auto bodyR = [&](uint4* bf) {
        floatx16 s = zero16();
        #pragma unroll
        for (int kc = 0; kc < 4; ++kc)
            s = MFMA32(as_s8(af[kc]), as_s8(bf[kc]), s);
        #pragma unroll
        for (int r = 0; r < 16; ++r) suml[r] += exp2a(s[r]);
    };

    loadB(bf0, 0);
    for (int jt = 0; jt < 16; jt += 2) {
        loadB(bf1, jt + 1);
        bodyR(bf0);
        if (jt + 2 < 16) loadB(bf0, jt + 2);
        bodyR(bf1);
    }

    #pragma unroll
    for (int r = 0; r < 16; ++r) {
        float v = suml[r];
        v += __shfl_xor(v, 1);
        v += __shfl_xor(v, 2);
        v += __shfl_xor(v, 4);
        v += __shfl_xor(v, 8);
        v += __shfl_xor(v, 16);
        suml[r] = v;
    }
    if (l31 == 0) {
        #pragma unroll
        for (int r = 0; r < 16; ++r) {
            int row = (r & 3) + 8 * (r >> 2) + 4 * hi;
            atomicAdd(&rl[(size_t)b * NN + i0 + row], suml[r]);
        }
    }
}

// ---------------------------------------------------------------------------
// scalehx (in-place): hxF *= 1/rl[i] per element (folds softmax denom into V).
// ---------------------------------------------------------------------------
__global__ __launch_bounds__(256) void scalehx_kernel(
    const float* __restrict__ rl, unsigned short* __restrict__ hxF)
{
    const int idx = blockIdx.x * 256 + threadIdx.x;   // 0..131071
    const int l = idx & 63;
    const int r = idx >> 6;
    const int ich = (r >> 1) & 1;
    const int tile = (r >> 2) & 127;
    const int b = r >> 9;
    const int i0 = tile * 32 + ich * 16 + (l >> 5) * 8;
    const float* rp = rl + (size_t)b * NN + i0;
    float4 ra = *reinterpret_cast<const float4*>(rp);
    float4 rb = *reinterpret_cast<const float4*>(rp + 4);
    uint4 v = *reinterpret_cast<uint4*>(hxF + (size_t)idx * 8);
    uint4 ov;
    ov.x = pack2bf(bf16lo(v.x) * rcpf(ra.x), bf16hi(v.x) * rcpf(ra.y));
    ov.y = pack2bf(bf16lo(v.y) * rcpf(ra.z), bf16hi(v.y) * rcpf(ra.w));
    ov.z = pack2bf(bf16lo(v.z) * rcpf(rb.x), bf16hi(v.z) * rcpf(rb.y));
    ov.w = pack2bf(bf16lo(v.w) * rcpf(rb.z), bf16hi(v.w) * rcpf(rb.w));
    *reinterpret_cast<uint4*>(hxF + (size_t)idx * 8) = ov;
}

// ---------------------------------------------------------------------------
// pv: opF[isb][n=j][cp=c] = sum_i 2^(S'_ij) * (hx/l)[c,i] over the block's
// i quarter-range. 4 waves = 2 igrp x 2 jgrp; per wave: j-sub 32, full c,
// 16 i-tiles. All loads lane-linear; LDS-reduce igrp pairs; epilogue writes
// outproj's 16x16x32 A-frag layout.
// ---------------------------------------------------------------------------
__global__ __launch_bounds__(256, 4) void pv_kernel(
    const unsigned short* __restrict__ fxF, const unsigned short* __restrict__ gxF,
    const unsigned short* __restrict__ hxF,
    float* __restrict__ opF0, float* __restrict__ opF1,
    float* __restrict__ opF2, float* __restrict__ opF3)
{
    const int t = threadIdx.x;
    const int w = t >> 6, l = t & 63, l31 = l & 31, hi = l >> 5;
    const int igrp = w >> 1, jgrp = w & 1;
    const int b = blockIdx.z;
    const int j0 = blockIdx.x * 64;
    const int isb = blockIdx.y;
    const int tbase = isb * 32 + igrp * 16;    // first 32-row i-tile index

    __shared__ float red[64 * 64];

    uint4 qf[4];
    {
        const unsigned short* gq =
            gxF + ((size_t)(b * 128 + (j0 >> 5) + jgrp)) * 2048 + (size_t)l * 8;
        #pragma unroll
        for (int kc = 0; kc < 4; ++kc)
            qf[kc] = *reinterpret_cast<const uint4*>(gq + kc * 512);
    }

    floatx16 acc0 = zero16(), acc1 = zero16();

    const unsigned short* fb = fxF + ((size_t)(b * 128 + tbase)) * 2048 + (size_t)l * 8;
    const unsigned short* vb = hxF + ((size_t)(b * 128 + tbase)) * 2048 + (size_t)l * 8;

    #pragma unroll 2
    for (int it = 0; it < 16; ++it) {
        const unsigned short* fp = fb + (size_t)it * 2048;
        const unsigned short* vp = vb + (size_t)it * 2048;
        uint4 af[4], vf[4];
        #pragma unroll
        for (int kc = 0; kc < 4; ++kc)
            af[kc] = *reinterpret_cast<const uint4*>(fp + kc * 512);
        vf[0] = *reinterpret_cast<const uint4*>(vp);           // ich0 part0
        vf[1] = *reinterpret_cast<const uint4*>(vp + 1024);    // ich1 part0
        vf[2] = *reinterpret_cast<const uint4*>(vp + 512);     // ich0 part1
        vf[3] = *reinterpret_cast<const uint4*>(vp + 1536);    // ich1 part1

        floatx16 s = zero16();
        #pragma unroll
        for (int kc = 0; kc < 4; ++kc)
            s = MFMA32(as_s8(af[kc]), as_s8(qf[kc]), s);

        float e[16];
        #pragma unroll
        for (int r = 0; r < 16; ++r) e[r] = exp2a(s[r]);

        unsigned u0 = cvtpk_bf16(e[0], e[1]);
        unsigned u1 = cvtpk_bf16(e[2], e[3]);
        unsigned u2 = cvtpk_bf16(e[4], e[5]);
        unsigned u3 = cvtpk_bf16(e[6], e[7]);
        pl32swap(u0, u2);
        pl32swap(u1, u3);
        uint4 pa0 = make_uint4(u0, u1, u2, u3);      // P k-chunk i 0..15
        unsigned u4 = cvtpk_bf16(e[8], e[9]);
        unsigned u5 = cvtpk_bf16(e[10], e[11]);
        unsigned u6 = cvtpk_bf16(e[12], e[13]);
        unsigned u7 = cvtpk_bf16(e[14], e[15]);
        pl32swap(u4, u6);
        pl32swap(u5, u7);
        uint4 pa1 = make_uint4(u4, u5, u6, u7);      // P k-chunk i 16..31

        acc0 = MFMA32(as_s8(pa0), as_s8(vf[0]), acc0);
        acc0 = MFMA32(as_s8(pa1), as_s8(vf[1]), acc0);
        acc1 = MFMA32(as_s8(pa0), as_s8(vf[2]), acc1);
        acc1 = MFMA32(as_s8(pa1), as_s8(vf[3]), acc1);
    }

    #pragma unroll
    for (int q = 0; q < 4; ++q)
        *reinterpret_cast<float4*>(&red[(q * 256 + t) * 4]) =
            make_float4(0.f, 0.f, 0.f, 0.f);
    __syncthreads();
    #pragma unroll
    for (int r = 0; r < 16; ++r) {
        int row = jgrp * 32 + (r & 3) + 8 * (r >> 2) + 4 * hi;
        atomicAdd(&red[row * 64 + l31],      acc0[r]);
        atomicAdd(&red[row * 64 + 32 + l31], acc1[r]);
    }
    __syncthreads();

    float* __restrict__ dst = (isb == 0) ? opF0 : ((isb == 1) ? opF1 : ((isb == 2) ? opF2 : opF3));
    #pragma unroll
    for (int q = 0; q < 4; ++q) {
        int idx = q * 256 + t;                 // 0..1023
        int e2  = idx & 1;
        int ll  = (idx >> 1) & 63;
        int ks  = (idx >> 7) & 1;
        int ntl = idx >> 8;
        int jloc = ntl * 16 + (ll & 15);
        int cp   = ks * 32 + ((ll >> 4) << 3) + e2 * 4;
        float4 v = *reinterpret_cast<const float4*>(&red[jloc * 64 + cp]);
        size_t off = (((size_t)(b * 256 + (j0 >> 4) + ntl) * 2 + ks) * 64 + ll) * 8 + e2 * 4;
        *reinterpret_cast<float4*>(dst + off) = v;
    }
}

// ---------------------------------------------------------------------------
// outproj (MFMA): y^T[n][co] = scale * sum_cp (sum4 opF)[n][cp] Wv^T[cp][co] + x.
// ---------------------------------------------------------------------------
__global__ __launch_bounds__(256) void outproj_kernel(
    const void* __restrict__ x,
    const void* __restrict__ Wv,
    const void* __restrict__ gamma,
    const int* __restrict__ dflag,
    const float* __restrict__ sig,
    const float* __restrict__ opF0, const float* __restrict__ opF1,
    const float* __restrict__ opF2, const float* __restrict__ opF3,
    void* __restrict__ y)
{
    const int f32 = *dflag;
    const int n0     = blockIdx.x * 64;
    const int cobase = blockIdx.y * 128;
    const int b      = blockIdx.z;
    const int t = threadIdx.x;
    const int wv = t >> 6, l = t & 63, l15 = l & 15, quad = l >> 4;
    const float scale = ldS(gamma, 0, f32) * sig[3];

    floatx4 acc[4][2];
    #pragma unroll
    for (int ns = 0; ns < 4; ++ns)
        #pragma unroll
        for (int ct = 0; ct < 2; ++ct) acc[ns][ct] = (floatx4){0.f, 0.f, 0.f, 0.f};

    #pragma unroll
    for (int ks = 0; ks < 2; ++ks) {
        short8 a[4];
        #pragma unroll
        for (int ns = 0; ns < 4; ++ns) {
            size_t fo = (((size_t)(b * 256 + (n0 >> 4) + ns) * 2 + ks) * 64 + l) * 8;
            float4 s0 = *reinterpret_cast<const float4*>(opF0 + fo);
            float4 s1 = *reinterpret_cast<const float4*>(opF1 + fo);
            float4 s2 = *reinterpret_cast<const float4*>(opF2 + fo);
            float4 s3 = *reinterpret_cast<const float4*>(opF3 + fo);
            float4 t0 = *reinterpret_cast<const float4*>(opF0 + fo + 4);
            float4 t1 = *reinterpret_cast<const float4*>(opF1 + fo + 4);
            float4 t2 = *reinterpret_cast<const float4*>(opF2 + fo + 4);
            float4 t3 = *reinterpret_cast<const float4*>(opF3 + fo + 4);
            float v0 = s0.x + s1.x + s2.x + s3.x;
            float v1 = s0.y + s1.y + s2.y + s3.y;
            float v2 = s0.z + s1.z + s2.z + s3.z;
            float v3 = s0.w + s1.w + s2.w + s3.w;
            float v4 = t0.x + t1.x + t2.x + t3.x;
            float v5 = t0.y + t1.y + t2.y + t3.y;
            float v6 = t0.z + t1.z + t2.z + t3.z;
            float v7 = t0.w + t1.w + t2.w + t3.w;
            uint4 au;
            au.x = pack2bf(v0, v1); au.y = pack2bf(v2, v3);
            au.z = pack2bf(v4, v5); au.w = pack2bf(v6, v7);
            a[ns] = *reinterpret_cast<short8*>(&au);
        }
        const int kb = ks * 32 + quad * 8;
        #pragma unroll
        for (int ct = 0; ct < 2; ++ct) {
            const int co = cobase + 32 * wv + 16 * ct + l15;
            short8 bfr = frag8(Wv, (long)co * CP + kb, f32);
            #pragma unroll
            for (int ns = 0; ns < 4; ++ns)
                acc[ns][ct] = __builtin_amdgcn_mfma_f32_16x16x32_bf16(
                    a[ns], bfr, acc[ns][ct], 0, 0, 0);
        }
    }

    #pragma unroll
    for (int ns = 0; ns < 4; ++ns)
        #pragma unroll
        for (int ct = 0; ct < 2; ++ct) {
            const int co = cobase + 32 * wv + 16 * ct + l15;
            const long base = ((long)b * CC + co) * NN + n0 + 16 * ns + quad * 4;
            float4 xv = ld4(x, base, f32);
            float o0 = fmaf(scale, acc[ns][ct][0], xv.x);
            float o1 = fmaf(scale, acc[ns][ct][1], xv.y);
            float o2 = fmaf(scale, acc[ns][ct][2], xv.z);
            float o3 = fmaf(scale, acc[ns][ct][3], xv.w);
            if (f32) {
                *reinterpret_cast<float4*>((float*)y + base) = make_float4(o0, o1, o2, o3);
            } else {
                uint2 o;
                o.x = pack2bf(o0, o1);
                o.y = pack2bf(o2, o3);
                *reinterpret_cast<uint2*>((unsigned short*)y + base) = o;
            }
        }
}

// ---------------------------------------------------------------------------
extern "C" void kernel_launch(void* const* d_in, const int* in_sizes, int n_in,
                              void* d_out, int out_size, void* d_ws, size_t ws_size,
                              hipStream_t stream)
{
    const void* x  = d_in[0];
    const void* Wf = d_in[1];
    const void* Wg = d_in[2];
    const void* Wh = d_in[3];
    const void* Wv = d_in[4];
    const void* uf = d_in[5];
    const void* ug = d_in[6];
    const void* uh = d_in[7];
    const void* uv = d_in[8];
    const void* gm = d_in[9];

    // ws: dfl | sig | rl (64KB) | opF0..3 (4x4MB) | fxF | gxF | hxF (2MB each)
    //     | xTF (16MB) | WF (192KB)
    char* base = (char*)d_ws;
    int*   dfl = (int*)(base);
    float* sig = (float*)(base + 512);
    float* rl  = (float*)(base + 1024);
    float* opF0 = (float*)(base + 1024 + 65536);
    float* opF1 = opF0 + (size_t)NB * NN * CP;
    float* opF2 = opF1 + (size_t)NB * NN * CP;
    float* opF3 = opF2 + (size_t)NB * NN * CP;
    unsigned short* fxF = (unsigned short*)(opF3 + (size_t)NB * NN * CP);
    unsigned short* gxF = fxF + (size_t)NB * CP * NN;
    unsigned short* hxF = gxF + (size_t)NB * CP * NN;
    unsigned short* xTF = hxF + (size_t)NB * CP * NN;
    unsigned short* WF  = xTF + (size_t)NB * CC * NN;

    hipMemsetAsync(rl, 0, (size_t)NB * NN * sizeof(float), stream);

    hipLaunchKernelGGL(detect_kernel, dim3(1), dim3(256), 0, stream,
                       (const unsigned*)x, dfl);
    hipLaunchKernelGGL(xpose_kernel, dim3(128, NB), dim3(256), 0, stream,
                       x, dfl, xTF);
    hipLaunchKernelGGL(sigma_kernel, dim3(4), dim3(512), 0, stream,
                       Wf, Wg, Wh, Wv, uf, ug, uh, uv, dfl, sig);
    hipLaunchKernelGGL(wprep_kernel, dim3(48), dim3(256), 0, stream,
                       Wf, Wg, Wh, dfl, sig, WF);
    hipLaunchKernelGGL(proj_kernel, dim3(32, NB, 6), dim3(256), 0, stream,
                       xTF, WF, fxF, gxF, hxF);
    hipLaunchKernelGGL(rowstats_kernel, dim3(NN / 128, 8, NB), dim3(256), 0, stream,
                       fxF, gxF, rl);
    hipLaunchKernelGGL(scalehx_kernel, dim3((NB * CP * NN / 8) / 256), dim3(256), 0, stream,
                       rl, hxF);
    hipLaunchKernelGGL(pv_kernel, dim3(NN / 64, 4, NB), dim3(256), 0, stream,
                       fxF, gxF, hxF, opF0, opF1, opF2, opF3);
    hipLaunchKernelGGL(outproj_kernel, dim3(NN / 64, CC / 128, NB), dim3(256), 0, stream,
                       x, Wv, gm, dfl, sig, opF0, opF1, opF2, opF3, d_out);
}